// Round 5
// baseline (299.418 us; speedup 1.0000x reference)
//
#include <hip/hip_runtime.h>
#include <hip/hip_bf16.h>

namespace {

constexpr int N = 4096;
constexpr int D = 512;
constexpr int BM = 64;    // 64x64 tile per block, 2x2 waves of 32x32 (R16 shape)
constexpr int BK = 64;    // K-step per fragment column-slice (64 fp8 bytes)
constexpr int KITERS = D / BK;  // 8 per phase
constexpr int NB = N / BM;      // 64 block-rows
constexpr int NBLK = NB * (NB + 1) / 2;  // 2080 upper-tri tiles (= 8 * 260)
constexpr int TILEB = BM * BK;  // 4 KB: one 64-row x 64-byte k-slice
constexpr int PANELB = BM * D;  // 32 KB: one 64-row fp8 panel
constexpr unsigned WAVES_PER_LAUNCH = (unsigned)NBLK * 4u;

// workspace layout (bytes)
constexpr size_t OFF_XB  = 0;                          // fp8 X  [N*D]  fragment-major
constexpr size_t OFF_YB  = (size_t)N * D;              // fp8 Y  [N*D]  fragment-major
constexpr size_t OFF_SQX = OFF_YB + (size_t)N * D;     // fp32 ||x_i||^2 [N]
constexpr size_t OFF_SQY = OFF_SQX + (size_t)N * 4;
constexpr size_t OFF_SX  = OFF_SQY + (size_t)N * 4;    // fp32 row sums KX [N]
constexpr size_t OFF_SY  = OFF_SX + (size_t)N * 4;     // fp32 row sums KY [N]
constexpr size_t OFF_T1  = OFF_SY + (size_t)N * 4;     // fp32 scalar sum(KX*KY)
constexpr size_t WS_NEED = OFF_T1 + 4;

// FRAGMENT-MAJOR ws layout: element (row r, k) of a 64x64B slice lives at
//   nib*1024 + quad*256 + cl*16 + pass*8 + j
// with nib=(r>>4)&3, cl=r&15, quad=(k>>3)&3, pass=k>>5, j=k&7.
// An MFMA operand fragment (16 rows x 64B of K) is a CONTIGUOUS 1KB at
// fragment base + lane*16 -- one coalesced global_load_dwordx4 per lane.
//
// R19: THE 8-WAVES/SIMD TIER. Measured facts: R17/R18 (2 waves/SIMD) ->
// main 90us; R16 (4 waves/SIMD, VGPR~104) -> main ~33us; HBM 1.7%,
// MfmaUtil 7%, loads are L2/L3-latency-bound -> time ~ 1/TLP. VGPR tiers
// (m69): <=64 -> 8 waves/SIMD. So: R16 structure squeezed into 64 VGPRs:
//   - __launch_bounds__(256, 8): compiler caps VGPR at 64; grid 2080
//     blocks = 8.125 blocks/CU -> ~full residency;
//   - kx carry lives in LDS (8KB/block, own-wave region, no barriers),
//     not in 8 VGPRs across the Y phase;
//   - idx/bI/bJ/wave forced scalar via readfirstlane -> decode + operand
//     base addressing is SGPR-only; per-lane state is just lane*16.
// R18's pipeline lesson: at 104 VGPR the compiler sank the prefetch loads
// back to their uses (the 2-set pipeline never reached the ISA). Don't
// fight the scheduler with registers -- buy TLP instead.
// Fused final via monotonic __device__ wave counter (R17b/R18, verified
// bit-exact): immune to workspace poison, exactly WAVES_PER_LAUNCH
// increments per launch/replay.
constexpr float D2_SKIP = 240.f;

typedef __attribute__((ext_vector_type(4))) float floatx4;
typedef __attribute__((ext_vector_type(2))) long longx2;

__device__ unsigned g_done;   // zero-initialized at module load; monotonic

__device__ inline unsigned short bf16bits(float f) {
  return __builtin_bit_cast(unsigned short, __float2bfloat16(f));
}

// fp32 -> fp8 e4m3 (OCP) conversion into the fragment-major layout + exact
// fp32 row squared norms. One wave per row; lane handles 8 consecutive
// elements -> one 8B store. Also zeroes sX/sY/T1.
__global__ void prep_kernel(const float* __restrict__ X, const float* __restrict__ Y,
                            unsigned char* __restrict__ Xf8, unsigned char* __restrict__ Yf8,
                            float* __restrict__ sqX, float* __restrict__ sqY,
                            float* __restrict__ sX, float* __restrict__ sY,
                            float* __restrict__ T1) {
  const int wave = threadIdx.x >> 6, lane = threadIdx.x & 63;
  const int row = blockIdx.x * 4 + wave;
  const int m = blockIdx.y;
  const float* __restrict__ src = m ? Y : X;
  unsigned char* __restrict__ dst = m ? Yf8 : Xf8;
  float* __restrict__ dsq = m ? sqY : sqX;

  if (threadIdx.x < 4) {
    float* z = m ? sY : sX;
    z[blockIdx.x * 4 + threadIdx.x] = 0.f;
  }
  if (blockIdx.x == 0 && m == 0 && threadIdx.x == 0) *T1 = 0.f;

  const float4* s4 = (const float4*)(src + (size_t)row * D);
  float4 v0 = s4[lane * 2];
  float4 v1 = s4[lane * 2 + 1];
  float acc = v0.x * v0.x + v0.y * v0.y + v0.z * v0.z + v0.w * v0.w
            + v1.x * v1.x + v1.y * v1.y + v1.z * v1.z + v1.w * v1.w;

  unsigned int w0 = 0, w1 = 0;
  w0 = __builtin_amdgcn_cvt_pk_fp8_f32(v0.x, v0.y, w0, false);
  w0 = __builtin_amdgcn_cvt_pk_fp8_f32(v0.z, v0.w, w0, true);
  w1 = __builtin_amdgcn_cvt_pk_fp8_f32(v1.x, v1.y, w1, false);
  w1 = __builtin_amdgcn_cvt_pk_fp8_f32(v1.z, v1.w, w1, true);
  const unsigned long long pk =
      (unsigned long long)w0 | ((unsigned long long)w1 << 32);

  // destination: k = lane*8 .. +8 of this row, fragment-major address
  const int p    = row >> 6;          // 64-row panel
  const int nib  = (row >> 4) & 3;
  const int cl   = row & 15;
  const int ks   = lane >> 3;         // 64-byte k-slice
  const int pass = (lane >> 2) & 1;
  const int quad = lane & 3;
  const size_t off = (size_t)p * PANELB + (size_t)ks * TILEB +
                     nib * 1024 + quad * 256 + cl * 16 + pass * 8;
  *(unsigned long long*)(dst + off) = pk;

#pragma unroll
  for (int mm = 32; mm >= 1; mm >>= 1) acc += __shfl_xor(acc, mm, 64);
  if (lane == 0) dsq[row] = acc;
}

// Upper-triangular fused Gram+RBF+reductions+final. 2080 blocks of 256
// threads; 2x2 waves of 32x32 per 64x64 tile; operands read directly from
// fragment-major global (L2/L3-hot). Target: 64 VGPR -> 8 waves/SIMD.
__launch_bounds__(256, 8)
__global__ void hsic_main(const unsigned char* __restrict__ Xf8,
                          const unsigned char* __restrict__ Yf8,
                          const float* __restrict__ sqX, const float* __restrict__ sqY,
                          float* __restrict__ sX, float* __restrict__ sY,
                          float* __restrict__ T1, float* __restrict__ out) {
  // per-wave kx carry: [wave][(mi*2+ni)*64 + lane] -- own-wave region only,
  // written in X epilogue / read in Y epilogue, no barriers needed.
  __shared__ unsigned long long kxs[4][256];   // 8 KB

  const int tid = threadIdx.x;
  const int lane = tid & 63;
  const int wv = __builtin_amdgcn_readfirstlane(tid >> 6);
  const int wm = wv >> 1, wn = wv & 1;

  // XCD-contiguous segment swizzle (bijection on [0,2080): 2080 = 8*260)
  const int b = blockIdx.x;
  int idx = __builtin_amdgcn_readfirstlane((b & 7) * (NBLK / 8) + (b >> 3));

  // triangular decode: idx -> (bI, bJ) with bJ >= bI (row-major triangle)
  const float nf = (float)NB + 0.5f;
  int bI = (int)(nf - sqrtf(nf * nf - 2.0f * (float)idx));
  if (bI < 0) bI = 0;
  if (bI >= NB) bI = NB - 1;
  while (bI * NB - bI * (bI - 1) / 2 > idx) --bI;
  while ((bI + 1) * NB - (bI + 1) * bI / 2 <= idx) ++bI;
  bI = __builtin_amdgcn_readfirstlane(bI);
  const int bJ = __builtin_amdgcn_readfirstlane(
      bI + (idx - (bI * NB - bI * (bI - 1) / 2)));
  const bool offdiag = (bI != bJ);

  const int quad = lane >> 4, cl = lane & 15;
  const int lane16 = lane << 4;

  // scalar bases (all wave-uniform); the only per-lane address term is lane16
  const unsigned char* gAx = Xf8 + (size_t)bI * PANELB + wm * 2048;
  const unsigned char* gBx = Xf8 + (size_t)bJ * PANELB + wn * 2048;
  const unsigned char* gAy = Yf8 + (size_t)bI * PANELB + wm * 2048;
  const unsigned char* gBy = Yf8 + (size_t)bJ * PANELB + wn * 2048;

  floatx4 acc[2][2];
#pragma unroll
  for (int i = 0; i < 2; ++i)
#pragma unroll
    for (int j = 0; j < 2; ++j) acc[i][j] = (floatx4){0.f, 0.f, 0.f, 0.f};

  const int Ib = bI * BM + wm * 32;
  const int Jb = bJ * BM + wn * 32;

  unsigned int fmask = 0;      // per-fragment wave-uniform "kx nonzero" bits
  float t1l = 0.f;

  // ---- X phase: 8 k-slices, operands straight from global ----
#pragma unroll
  for (int ks = 0; ks < KITERS; ++ks) {
    longx2 af[2], bf[2];
#pragma unroll
    for (int mi = 0; mi < 2; ++mi)
      af[mi] = *(const longx2*)(gAx + (size_t)ks * TILEB + mi * 1024 + lane16);
#pragma unroll
    for (int ni = 0; ni < 2; ++ni)
      bf[ni] = *(const longx2*)(gBx + (size_t)ks * TILEB + ni * 1024 + lane16);
#pragma unroll
    for (int mi = 0; mi < 2; ++mi)
#pragma unroll
      for (int ni = 0; ni < 2; ++ni) {
        acc[mi][ni] = __builtin_amdgcn_mfma_f32_16x16x32_fp8_fp8(af[mi][0], bf[ni][0], acc[mi][ni], 0, 0, 0);
        acc[mi][ni] = __builtin_amdgcn_mfma_f32_16x16x32_fp8_fp8(af[mi][1], bf[ni][1], acc[mi][ni], 0, 0, 0);
      }
  }

  // ---- X epilogue: acc -> kx; sX atomics; kx -> LDS; reset acc ----
  // C/D layout (m89): col = lane&15, row = quad*4 + reg
  {
    float rx[2][4];
    float cx[2];
#pragma unroll
    for (int mi = 0; mi < 2; ++mi)
#pragma unroll
      for (int r = 0; r < 4; ++r) rx[mi][r] = 0.f;
#pragma unroll
    for (int ni = 0; ni < 2; ++ni) cx[ni] = 0.f;

#pragma unroll
    for (int mi = 0; mi < 2; ++mi) {
      const int ig0 = Ib + mi * 16 + quad * 4;
      float sxi[4];
#pragma unroll
      for (int r = 0; r < 4; ++r) sxi[r] = sqX[ig0 + r];
#pragma unroll
      for (int ni = 0; ni < 2; ++ni) {
        const int jg = Jb + ni * 16 + cl;
        const float sxj = sqX[jg];
        float d2x[4];
        bool lflag = false;
#pragma unroll
        for (int r = 0; r < 4; ++r) {
          const int ig = ig0 + r;
          d2x[r] = sxi[r] + sxj - 2.f * acc[mi][ni][r];
          lflag |= (d2x[r] < D2_SKIP) | (ig == jg);
        }
        float kxv[4] = {0.f, 0.f, 0.f, 0.f};
        if (__any(lflag)) {   // wave-uniform; skipped frags are exactly 0
          fmask |= (1u << (mi * 2 + ni));
#pragma unroll
          for (int r = 0; r < 4; ++r) {
            const int ig = ig0 + r;
            kxv[r] = (ig == jg) ? 1.f : __expf(-0.5f * d2x[r]);
            rx[mi][r] += kxv[r];
            cx[ni] += kxv[r];
          }
        }
        const unsigned p0 = (unsigned)bf16bits(kxv[0]) | ((unsigned)bf16bits(kxv[1]) << 16);
        const unsigned p1 = (unsigned)bf16bits(kxv[2]) | ((unsigned)bf16bits(kxv[3]) << 16);
        kxs[wv][(mi * 2 + ni) * 64 + lane] =
            (unsigned long long)p0 | ((unsigned long long)p1 << 32);
        // reset acc for the Y phase
        acc[mi][ni] = (floatx4){0.f, 0.f, 0.f, 0.f};
      }
    }

    if (fmask != 0) {
      // row sums: reduce across the 16 columns (lanes cl=0..15 per quad)
#pragma unroll
      for (int mi = 0; mi < 2; ++mi)
#pragma unroll
        for (int r = 0; r < 4; ++r) {
          float vx = rx[mi][r];
#pragma unroll
          for (int mm = 1; mm < 16; mm <<= 1) vx += __shfl_xor(vx, mm, 16);
          rx[mi][r] = vx;
        }
      if (cl == 0) {
#pragma unroll
        for (int mi = 0; mi < 2; ++mi)
#pragma unroll
          for (int r = 0; r < 4; ++r)
            atomicAdd(&sX[Ib + mi * 16 + quad * 4 + r], rx[mi][r]);
      }
      if (offdiag) {
#pragma unroll
        for (int ni = 0; ni < 2; ++ni) {
          float vx = cx[ni];
          vx += __shfl_xor(vx, 16, 64);
          vx += __shfl_xor(vx, 32, 64);
          if (quad == 0) atomicAdd(&sX[Jb + ni * 16 + cl], vx);
        }
      }
    }
  }

  // ---- Y phase ----
#pragma unroll
  for (int ks = 0; ks < KITERS; ++ks) {
    longx2 af[2], bf[2];
#pragma unroll
    for (int mi = 0; mi < 2; ++mi)
      af[mi] = *(const longx2*)(gAy + (size_t)ks * TILEB + mi * 1024 + lane16);
#pragma unroll
    for (int ni = 0; ni < 2; ++ni)
      bf[ni] = *(const longx2*)(gBy + (size_t)ks * TILEB + ni * 1024 + lane16);
#pragma unroll
    for (int mi = 0; mi < 2; ++mi)
#pragma unroll
      for (int ni = 0; ni < 2; ++ni) {
        acc[mi][ni] = __builtin_amdgcn_mfma_f32_16x16x32_fp8_fp8(af[mi][0], bf[ni][0], acc[mi][ni], 0, 0, 0);
        acc[mi][ni] = __builtin_amdgcn_mfma_f32_16x16x32_fp8_fp8(af[mi][1], bf[ni][1], acc[mi][ni], 0, 0, 0);
      }
  }

  // ---- Y epilogue ----
  {
    float ry[2][4];
    float cy[2];
    bool anyy = false;
#pragma unroll
    for (int mi = 0; mi < 2; ++mi)
#pragma unroll
      for (int r = 0; r < 4; ++r) ry[mi][r] = 0.f;
#pragma unroll
    for (int ni = 0; ni < 2; ++ni) cy[ni] = 0.f;

#pragma unroll
    for (int mi = 0; mi < 2; ++mi) {
      const int ig0 = Ib + mi * 16 + quad * 4;
      float syi[4];
#pragma unroll
      for (int r = 0; r < 4; ++r) syi[r] = sqY[ig0 + r];
#pragma unroll
      for (int ni = 0; ni < 2; ++ni) {
        const int jg = Jb + ni * 16 + cl;
        const float syj = sqY[jg];
        float d2y[4];
        bool lflag = false;
#pragma unroll
        for (int r = 0; r < 4; ++r) {
          const int ig = ig0 + r;
          d2y[r] = syi[r] + syj - 2.f * acc[mi][ni][r];
          lflag |= (d2y[r] < D2_SKIP) | (ig == jg);
        }
        const bool xb = (fmask >> (mi * 2 + ni)) & 1u;  // wave-uniform
        if (__any(lflag) || xb) {
          anyy = true;
          float kyv[4];
#pragma unroll
          for (int r = 0; r < 4; ++r) {
            const int ig = ig0 + r;
            kyv[r] = (ig == jg) ? 1.f : __expf(-0.5f * d2y[r]);
            ry[mi][r] += kyv[r];
            cy[ni] += kyv[r];
          }
          if (xb) {
            const unsigned long long pk = kxs[wv][(mi * 2 + ni) * 64 + lane];
            const unsigned p0 = (unsigned)pk;
            const unsigned p1 = (unsigned)(pk >> 32);
            const float kx0 = __builtin_bit_cast(float, (p0 & 0xFFFFu) << 16);
            const float kx1 = __builtin_bit_cast(float, p0 & 0xFFFF0000u);
            const float kx2 = __builtin_bit_cast(float, (p1 & 0xFFFFu) << 16);
            const float kx3 = __builtin_bit_cast(float, p1 & 0xFFFF0000u);
            t1l += kx0 * kyv[0] + kx1 * kyv[1] + kx2 * kyv[2] + kx3 * kyv[3];
          }
        }
      }
    }

    if (anyy) {
#pragma unroll
      for (int mi = 0; mi < 2; ++mi)
#pragma unroll
        for (int r = 0; r < 4; ++r) {
          float vy = ry[mi][r];
#pragma unroll
          for (int mm = 1; mm < 16; mm <<= 1) vy += __shfl_xor(vy, mm, 16);
          ry[mi][r] = vy;
        }
      if (cl == 0) {
#pragma unroll
        for (int mi = 0; mi < 2; ++mi)
#pragma unroll
          for (int r = 0; r < 4; ++r)
            atomicAdd(&sY[Ib + mi * 16 + quad * 4 + r], ry[mi][r]);
      }
      if (offdiag) {
#pragma unroll
        for (int ni = 0; ni < 2; ++ni) {
          float vy = cy[ni];
          vy += __shfl_xor(vy, 16, 64);
          vy += __shfl_xor(vy, 32, 64);
          if (quad == 0) atomicAdd(&sY[Jb + ni * 16 + cl], vy);
        }
      }
    }
  }

  // T1 wave reduction (off-diagonal tiles count twice by symmetry)
  if (fmask != 0) {
    t1l *= offdiag ? 2.f : 1.f;
#pragma unroll
    for (int mm = 1; mm < 64; mm <<= 1) t1l += __shfl_xor(t1l, mm, 64);
    if (lane == 0 && t1l != 0.f) atomicAdd(T1, t1l);
  }

  // ---- fused final: per-WAVE completion counter; last wave computes HSIC.
  // All prior device-scope atomics are ordered before the release
  // fetch_add; the last wave's acquire makes them visible. g_done is a
  // __device__ global: unaffected by workspace poison, monotonic across
  // launches and rocprof replays (each launch adds exactly WAVES_PER_LAUNCH).
  int am_last = 0;
  if (lane == 0) {
    unsigned old = __hip_atomic_fetch_add(&g_done, 1u, __ATOMIC_ACQ_REL,
                                          __HIP_MEMORY_SCOPE_AGENT);
    am_last = ((old + 1u) % WAVES_PER_LAUNCH) == 0u;
  }
  am_last = __shfl(am_last, 0, 64);
  if (am_last) {
    float dp = 0.f, sa = 0.f, sb = 0.f;
    for (int i = lane; i < N; i += 64) {
      float a = __hip_atomic_load(&sX[i], __ATOMIC_RELAXED, __HIP_MEMORY_SCOPE_AGENT);
      float bv = __hip_atomic_load(&sY[i], __ATOMIC_RELAXED, __HIP_MEMORY_SCOPE_AGENT);
      dp += a * bv; sa += a; sb += bv;
    }
#pragma unroll
    for (int mm = 1; mm < 64; mm <<= 1) {
      dp += __shfl_xor(dp, mm, 64);
      sa += __shfl_xor(sa, mm, 64);
      sb += __shfl_xor(sb, mm, 64);
    }
    if (lane == 0) {
      const float t1 = __hip_atomic_load(T1, __ATOMIC_RELAXED, __HIP_MEMORY_SCOPE_AGENT);
      const float n = (float)N;
      const float total = t1 - (2.f / n) * dp + (sa * sb) / (n * n);
      out[0] = total / ((n - 1.f) * (n - 1.f));
    }
  }
}

}  // namespace

extern "C" void kernel_launch(void* const* d_in, const int* in_sizes, int n_in,
                              void* d_out, int out_size, void* d_ws, size_t ws_size,
                              hipStream_t stream) {
  const float* X = (const float*)d_in[0];
  const float* Y = (const float*)d_in[1];
  char* ws = (char*)d_ws;
  if (ws_size < WS_NEED) return;

  unsigned char* Xf8 = (unsigned char*)(ws + OFF_XB);
  unsigned char* Yf8 = (unsigned char*)(ws + OFF_YB);
  float* sqX = (float*)(ws + OFF_SQX);
  float* sqY = (float*)(ws + OFF_SQY);
  float* sX  = (float*)(ws + OFF_SX);
  float* sY  = (float*)(ws + OFF_SY);
  float* T1  = (float*)(ws + OFF_T1);
  float* out = (float*)d_out;

  prep_kernel<<<dim3(N / 4, 2), 256, 0, stream>>>(X, Y, Xf8, Yf8, sqX, sqY, sX, sY, T1);
  hsic_main<<<NBLK, 256, 0, stream>>>(Xf8, Yf8, sqX, sqY, sX, sY, T1, out);
}

// Round 6
// 242.885 us; speedup vs baseline: 1.2328x; 1.2328x over previous
//
#include <hip/hip_runtime.h>

namespace {

constexpr int N = 4096;
constexpr int D = 512;
constexpr int BM = 64;    // 64x64 tile per block, 2x2 waves of 32x32
constexpr int BK = 64;    // K-step per fragment column-slice (64 fp8 bytes)
constexpr int KITERS = D / BK;  // 8 (X and Y interleaved in the same loop)
constexpr int NB = N / BM;      // 64 block-rows
constexpr int NBLK = NB * (NB + 1) / 2;  // 2080 upper-tri tiles (= 8 * 260)
constexpr int TILEB = BM * BK;  // 4 KB: one 64-row x 64-byte k-slice
constexpr int PANELB = BM * D;  // 32 KB: one 64-row fp8 panel
constexpr unsigned WAVES_PER_LAUNCH = (unsigned)NBLK * 4u;

// workspace layout (bytes)
constexpr size_t OFF_XB  = 0;                          // fp8 X  [N*D]  fragment-major
constexpr size_t OFF_YB  = (size_t)N * D;              // fp8 Y  [N*D]  fragment-major
constexpr size_t OFF_SQX = OFF_YB + (size_t)N * D;     // fp32 ||x_i||^2 [N]
constexpr size_t OFF_SQY = OFF_SQX + (size_t)N * 4;
constexpr size_t OFF_SX  = OFF_SQY + (size_t)N * 4;    // fp32 row sums KX [N]
constexpr size_t OFF_SY  = OFF_SX + (size_t)N * 4;     // fp32 row sums KY [N]
constexpr size_t OFF_T1  = OFF_SY + (size_t)N * 4;     // fp32 scalar sum(KX*KY)
constexpr size_t WS_NEED = OFF_T1 + 4;

// FRAGMENT-MAJOR ws layout: element (row r, k) of a 64x64B slice lives at
//   nib*1024 + quad*256 + cl*16 + pass*8 + j
// with nib=(r>>4)&3, cl=r&15, quad=(k>>3)&3, pass=k>>5, j=k&7.
// An MFMA operand fragment (16 rows x 64B of K) is a CONTIGUOUS 1KB at
// fragment base + lane*16 -- one coalesced global_load_dwordx4 per lane.
//
// R20: MERGED X/Y K-LOOP + 6-WAVE TIER.
// Ladder of measured facts: 2 waves/SIMD -> main 90us (R17/R18, latency-
// bound: HBM 1.7%, MfmaUtil 7%); ~4 waves -> main ~30 (R16); forcing the
// 8-wave tier (R19, cap 64) -> VGPR 32 + 18.7MB scratch spills -> 233us.
// So: occupancy is THE lever, 8-wave tier unreachable, 5-6 wave band open.
//   - X and Y Grams accumulate in ONE k-loop (accX,accY = 32 regs): both
//     finish together, so the Y epilogue reads kx directly from fp32 --
//     the entire kxp pack/LDS-carry/unpack machinery is deleted;
//   - each iter has 2 independent load groups + 2 independent 8-MFMA
//     chains: loadY hides under mfmaX and vice versa even when the
//     compiler sinks loads to uses (its R18-demonstrated habit);
//   - __launch_bounds__(256,6): cap ~85 regs ~= the natural live set ->
//     6 waves/SIMD, no spills (go/no-go counter: WRITE_SIZE ~0.2MB).
// Numerics: identical per-phase MFMA accumulation order; t1 now uses fp32
// kx (prev: bf16-rounded) -- for this data kx in {0,1} exactly (all
// off-diag d2 ~ 700-1000 >> 240 underflow exactly to +0 in fp32), so the
// result is bit-identical; skipped fragments contribute exact zeros.
// Fused final via monotonic __device__ wave counter (bit-exact since R17):
// immune to workspace poison; exactly WAVES_PER_LAUNCH increments per
// launch/replay, (old+1)%WAVES_PER_LAUNCH==0 selects the last wave.
constexpr float D2_SKIP = 240.f;

typedef __attribute__((ext_vector_type(4))) float floatx4;
typedef __attribute__((ext_vector_type(2))) long longx2;

__device__ unsigned g_done;   // zero-initialized at module load; monotonic

// fp32 -> fp8 e4m3 (OCP) conversion into the fragment-major layout + exact
// fp32 row squared norms. One wave per row; lane handles 8 consecutive
// elements -> one 8B store. Also zeroes sX/sY/T1.
__global__ void prep_kernel(const float* __restrict__ X, const float* __restrict__ Y,
                            unsigned char* __restrict__ Xf8, unsigned char* __restrict__ Yf8,
                            float* __restrict__ sqX, float* __restrict__ sqY,
                            float* __restrict__ sX, float* __restrict__ sY,
                            float* __restrict__ T1) {
  const int wave = threadIdx.x >> 6, lane = threadIdx.x & 63;
  const int row = blockIdx.x * 4 + wave;
  const int m = blockIdx.y;
  const float* __restrict__ src = m ? Y : X;
  unsigned char* __restrict__ dst = m ? Yf8 : Xf8;
  float* __restrict__ dsq = m ? sqY : sqX;

  if (threadIdx.x < 4) {
    float* z = m ? sY : sX;
    z[blockIdx.x * 4 + threadIdx.x] = 0.f;
  }
  if (blockIdx.x == 0 && m == 0 && threadIdx.x == 0) *T1 = 0.f;

  const float4* s4 = (const float4*)(src + (size_t)row * D);
  float4 v0 = s4[lane * 2];
  float4 v1 = s4[lane * 2 + 1];
  float acc = v0.x * v0.x + v0.y * v0.y + v0.z * v0.z + v0.w * v0.w
            + v1.x * v1.x + v1.y * v1.y + v1.z * v1.z + v1.w * v1.w;

  unsigned int w0 = 0, w1 = 0;
  w0 = __builtin_amdgcn_cvt_pk_fp8_f32(v0.x, v0.y, w0, false);
  w0 = __builtin_amdgcn_cvt_pk_fp8_f32(v0.z, v0.w, w0, true);
  w1 = __builtin_amdgcn_cvt_pk_fp8_f32(v1.x, v1.y, w1, false);
  w1 = __builtin_amdgcn_cvt_pk_fp8_f32(v1.z, v1.w, w1, true);
  const unsigned long long pk =
      (unsigned long long)w0 | ((unsigned long long)w1 << 32);

  // destination: k = lane*8 .. +8 of this row, fragment-major address
  const int p    = row >> 6;          // 64-row panel
  const int nib  = (row >> 4) & 3;
  const int cl   = row & 15;
  const int ks   = lane >> 3;         // 64-byte k-slice
  const int pass = (lane >> 2) & 1;
  const int quad = lane & 3;
  const size_t off = (size_t)p * PANELB + (size_t)ks * TILEB +
                     nib * 1024 + quad * 256 + cl * 16 + pass * 8;
  *(unsigned long long*)(dst + off) = pk;

#pragma unroll
  for (int mm = 32; mm >= 1; mm >>= 1) acc += __shfl_xor(acc, mm, 64);
  if (lane == 0) dsq[row] = acc;
}

// Upper-triangular fused Gram(X)+Gram(Y)+RBF+reductions+final. 2080 blocks
// of 256 threads; 2x2 waves of 32x32 per 64x64 tile; operands read directly
// from fragment-major global (L2/L3-hot). Target: <=85 regs, 6 waves/SIMD.
__launch_bounds__(256, 6)
__global__ void hsic_main(const unsigned char* __restrict__ Xf8,
                          const unsigned char* __restrict__ Yf8,
                          const float* __restrict__ sqX, const float* __restrict__ sqY,
                          float* __restrict__ sX, float* __restrict__ sY,
                          float* __restrict__ T1, float* __restrict__ out) {
  const int tid = threadIdx.x;
  const int lane = tid & 63;
  const int wv = __builtin_amdgcn_readfirstlane(tid >> 6);
  const int wm = wv >> 1, wn = wv & 1;

  // XCD-contiguous segment swizzle (bijection on [0,2080): 2080 = 8*260)
  const int b = blockIdx.x;
  int idx = __builtin_amdgcn_readfirstlane((b & 7) * (NBLK / 8) + (b >> 3));

  // triangular decode: idx -> (bI, bJ) with bJ >= bI (row-major triangle)
  const float nf = (float)NB + 0.5f;
  int bI = (int)(nf - sqrtf(nf * nf - 2.0f * (float)idx));
  if (bI < 0) bI = 0;
  if (bI >= NB) bI = NB - 1;
  while (bI * NB - bI * (bI - 1) / 2 > idx) --bI;
  while ((bI + 1) * NB - (bI + 1) * bI / 2 <= idx) ++bI;
  bI = __builtin_amdgcn_readfirstlane(bI);
  const int bJ = __builtin_amdgcn_readfirstlane(
      bI + (idx - (bI * NB - bI * (bI - 1) / 2)));
  const bool offdiag = (bI != bJ);

  const int quad = lane >> 4, cl = lane & 15;
  const int lane16 = lane << 4;

  // scalar bases (all wave-uniform); the only per-lane address term is lane16
  const unsigned char* gAx = Xf8 + (size_t)bI * PANELB + wm * 2048;
  const unsigned char* gBx = Xf8 + (size_t)bJ * PANELB + wn * 2048;
  const unsigned char* gAy = Yf8 + (size_t)bI * PANELB + wm * 2048;
  const unsigned char* gBy = Yf8 + (size_t)bJ * PANELB + wn * 2048;

  floatx4 accX[2][2], accY[2][2];
#pragma unroll
  for (int i = 0; i < 2; ++i)
#pragma unroll
    for (int j = 0; j < 2; ++j) {
      accX[i][j] = (floatx4){0.f, 0.f, 0.f, 0.f};
      accY[i][j] = (floatx4){0.f, 0.f, 0.f, 0.f};
    }

  const int Ib = bI * BM + wm * 32;
  const int Jb = bJ * BM + wn * 32;

  // ---- merged k-loop: X and Y Grams interleaved. Two independent load
  // groups + two independent MFMA chains per iter -> loadY latency hides
  // under mfmaX and loadX(k+1) under mfmaY, even with compiler-sunk loads.
#pragma unroll
  for (int ks = 0; ks < KITERS; ++ks) {
    longx2 afx[2], bfx[2], afy[2], bfy[2];
#pragma unroll
    for (int mi = 0; mi < 2; ++mi)
      afx[mi] = *(const longx2*)(gAx + (size_t)ks * TILEB + mi * 1024 + lane16);
#pragma unroll
    for (int ni = 0; ni < 2; ++ni)
      bfx[ni] = *(const longx2*)(gBx + (size_t)ks * TILEB + ni * 1024 + lane16);
#pragma unroll
    for (int mi = 0; mi < 2; ++mi)
      afy[mi] = *(const longx2*)(gAy + (size_t)ks * TILEB + mi * 1024 + lane16);
#pragma unroll
    for (int ni = 0; ni < 2; ++ni)
      bfy[ni] = *(const longx2*)(gBy + (size_t)ks * TILEB + ni * 1024 + lane16);

#pragma unroll
    for (int mi = 0; mi < 2; ++mi)
#pragma unroll
      for (int ni = 0; ni < 2; ++ni) {
        accX[mi][ni] = __builtin_amdgcn_mfma_f32_16x16x32_fp8_fp8(afx[mi][0], bfx[ni][0], accX[mi][ni], 0, 0, 0);
        accX[mi][ni] = __builtin_amdgcn_mfma_f32_16x16x32_fp8_fp8(afx[mi][1], bfx[ni][1], accX[mi][ni], 0, 0, 0);
      }
#pragma unroll
    for (int mi = 0; mi < 2; ++mi)
#pragma unroll
      for (int ni = 0; ni < 2; ++ni) {
        accY[mi][ni] = __builtin_amdgcn_mfma_f32_16x16x32_fp8_fp8(afy[mi][0], bfy[ni][0], accY[mi][ni], 0, 0, 0);
        accY[mi][ni] = __builtin_amdgcn_mfma_f32_16x16x32_fp8_fp8(afy[mi][1], bfy[ni][1], accY[mi][ni], 0, 0, 0);
      }
  }

  // ---- merged epilogue: kx, ky, row/col sums, t1 -- all from fp32 accs.
  // C/D layout (m89): col = lane&15, row = quad*4 + reg
  float t1l = 0.f;
  {
    float rx[2][4], ry[2][4];
    float cx[2], cy[2];
    bool anyx = false, anyy = false;
#pragma unroll
    for (int mi = 0; mi < 2; ++mi)
#pragma unroll
      for (int r = 0; r < 4; ++r) { rx[mi][r] = 0.f; ry[mi][r] = 0.f; }
#pragma unroll
    for (int ni = 0; ni < 2; ++ni) { cx[ni] = 0.f; cy[ni] = 0.f; }

#pragma unroll
    for (int mi = 0; mi < 2; ++mi) {
      const int ig0 = Ib + mi * 16 + quad * 4;
      float sxi[4], syi[4];
#pragma unroll
      for (int r = 0; r < 4; ++r) { sxi[r] = sqX[ig0 + r]; syi[r] = sqY[ig0 + r]; }
#pragma unroll
      for (int ni = 0; ni < 2; ++ni) {
        const int jg = Jb + ni * 16 + cl;
        const float sxj = sqX[jg];
        const float syj = sqY[jg];
        float d2x[4], d2y[4];
        bool fx = false, fy = false;
#pragma unroll
        for (int r = 0; r < 4; ++r) {
          const int ig = ig0 + r;
          d2x[r] = sxi[r] + sxj - 2.f * accX[mi][ni][r];
          d2y[r] = syi[r] + syj - 2.f * accY[mi][ni][r];
          fx |= (d2x[r] < D2_SKIP) | (ig == jg);
          fy |= (d2y[r] < D2_SKIP) | (ig == jg);
        }
        float kxv[4] = {0.f, 0.f, 0.f, 0.f};
        float kyv[4] = {0.f, 0.f, 0.f, 0.f};
        if (__any(fx)) {   // wave-uniform; skipped frags are exact zeros
          anyx = true;
#pragma unroll
          for (int r = 0; r < 4; ++r) {
            const int ig = ig0 + r;
            kxv[r] = (ig == jg) ? 1.f : __expf(-0.5f * d2x[r]);
            rx[mi][r] += kxv[r];
            cx[ni] += kxv[r];
          }
        }
        if (__any(fy)) {
          anyy = true;
#pragma unroll
          for (int r = 0; r < 4; ++r) {
            const int ig = ig0 + r;
            kyv[r] = (ig == jg) ? 1.f : __expf(-0.5f * d2y[r]);
            ry[mi][r] += kyv[r];
            cy[ni] += kyv[r];
          }
          t1l += kxv[0] * kyv[0] + kxv[1] * kyv[1] + kxv[2] * kyv[2] + kxv[3] * kyv[3];
        }
      }
    }

    // row sums: reduce across the 16 columns (lanes cl=0..15 per quad)
    if (anyx) {
#pragma unroll
      for (int mi = 0; mi < 2; ++mi)
#pragma unroll
        for (int r = 0; r < 4; ++r) {
          float vx = rx[mi][r];
#pragma unroll
          for (int mm = 1; mm < 16; mm <<= 1) vx += __shfl_xor(vx, mm, 16);
          rx[mi][r] = vx;
        }
      if (cl == 0) {
#pragma unroll
        for (int mi = 0; mi < 2; ++mi)
#pragma unroll
          for (int r = 0; r < 4; ++r)
            atomicAdd(&sX[Ib + mi * 16 + quad * 4 + r], rx[mi][r]);
      }
      if (offdiag) {
#pragma unroll
        for (int ni = 0; ni < 2; ++ni) {
          float vx = cx[ni];
          vx += __shfl_xor(vx, 16, 64);
          vx += __shfl_xor(vx, 32, 64);
          if (quad == 0) atomicAdd(&sX[Jb + ni * 16 + cl], vx);
        }
      }
    }
    if (anyy) {
#pragma unroll
      for (int mi = 0; mi < 2; ++mi)
#pragma unroll
        for (int r = 0; r < 4; ++r) {
          float vy = ry[mi][r];
#pragma unroll
          for (int mm = 1; mm < 16; mm <<= 1) vy += __shfl_xor(vy, mm, 16);
          ry[mi][r] = vy;
        }
      if (cl == 0) {
#pragma unroll
        for (int mi = 0; mi < 2; ++mi)
#pragma unroll
          for (int r = 0; r < 4; ++r)
            atomicAdd(&sY[Ib + mi * 16 + quad * 4 + r], ry[mi][r]);
      }
      if (offdiag) {
#pragma unroll
        for (int ni = 0; ni < 2; ++ni) {
          float vy = cy[ni];
          vy += __shfl_xor(vy, 16, 64);
          vy += __shfl_xor(vy, 32, 64);
          if (quad == 0) atomicAdd(&sY[Jb + ni * 16 + cl], vy);
        }
      }
    }

    // T1 wave reduction (off-diagonal tiles count twice by symmetry)
    if (anyy) {
      t1l *= offdiag ? 2.f : 1.f;
#pragma unroll
      for (int mm = 1; mm < 64; mm <<= 1) t1l += __shfl_xor(t1l, mm, 64);
      if (lane == 0 && t1l != 0.f) atomicAdd(T1, t1l);
    }
  }

  // ---- fused final: per-WAVE completion counter; last wave computes HSIC.
  // All prior device-scope atomics are ordered before the release
  // fetch_add; the last wave's acquire makes them visible (subsequent
  // loads of this wave happen after the acquire). g_done is a __device__
  // global: unaffected by workspace poison, monotonic across launches and
  // rocprof replays (each launch adds exactly WAVES_PER_LAUNCH).
  int am_last = 0;
  if (lane == 0) {
    unsigned old = __hip_atomic_fetch_add(&g_done, 1u, __ATOMIC_ACQ_REL,
                                          __HIP_MEMORY_SCOPE_AGENT);
    am_last = ((old + 1u) % WAVES_PER_LAUNCH) == 0u;
  }
  am_last = __shfl(am_last, 0, 64);
  if (am_last) {
    float dp = 0.f, sa = 0.f, sb = 0.f;
    // plain vector loads are safe here: the acquire above happens-before
    // these reads and all writers released via the same atomic location.
    for (int i = lane * 4; i < N; i += 256) {
      const float4 a4 = *(const float4*)&sX[i];
      const float4 b4 = *(const float4*)&sY[i];
      dp += a4.x * b4.x + a4.y * b4.y + a4.z * b4.z + a4.w * b4.w;
      sa += a4.x + a4.y + a4.z + a4.w;
      sb += b4.x + b4.y + b4.z + b4.w;
    }
#pragma unroll
    for (int mm = 1; mm < 64; mm <<= 1) {
      dp += __shfl_xor(dp, mm, 64);
      sa += __shfl_xor(sa, mm, 64);
      sb += __shfl_xor(sb, mm, 64);
    }
    if (lane == 0) {
      const float t1 = __hip_atomic_load(T1, __ATOMIC_RELAXED, __HIP_MEMORY_SCOPE_AGENT);
      const float n = (float)N;
      const float total = t1 - (2.f / n) * dp + (sa * sb) / (n * n);
      out[0] = total / ((n - 1.f) * (n - 1.f));
    }
  }
}

}  // namespace

extern "C" void kernel_launch(void* const* d_in, const int* in_sizes, int n_in,
                              void* d_out, int out_size, void* d_ws, size_t ws_size,
                              hipStream_t stream) {
  const float* X = (const float*)d_in[0];
  const float* Y = (const float*)d_in[1];
  char* ws = (char*)d_ws;
  if (ws_size < WS_NEED) return;

  unsigned char* Xf8 = (unsigned char*)(ws + OFF_XB);
  unsigned char* Yf8 = (unsigned char*)(ws + OFF_YB);
  float* sqX = (float*)(ws + OFF_SQX);
  float* sqY = (float*)(ws + OFF_SQY);
  float* sX  = (float*)(ws + OFF_SX);
  float* sY  = (float*)(ws + OFF_SY);
  float* T1  = (float*)(ws + OFF_T1);
  float* out = (float*)d_out;

  prep_kernel<<<dim3(N / 4, 2), 256, 0, stream>>>(X, Y, Xf8, Yf8, sqX, sqY, sX, sY, T1);
  hsic_main<<<NBLK, 256, 0, stream>>>(Xf8, Yf8, sqX, sqY, sX, sY, T1, out);
}

// Round 8
// 225.703 us; speedup vs baseline: 1.3266x; 1.0761x over previous
//
#include <hip/hip_runtime.h>
#include <hip/hip_bf16.h>

namespace {

constexpr int N = 4096;
constexpr int D = 512;
constexpr int BM = 64;    // block tile 64x64; 2080 blocks, 2x2 waves of 32x32
constexpr int BK = 64;    // K-step per fragment column-slice (64 fp8 bytes)
constexpr int KITERS = D / BK;  // 8 per phase
constexpr int NB = N / BM;      // 64 block-rows
constexpr int NBLK = NB * (NB + 1) / 2;  // 2080 upper-tri tiles (= 8 * 260)
constexpr int TILEB = BM * BK;  // 4 KB: one 64-row x 64-byte k-slice
constexpr int PANELB = BM * D;  // 32 KB: one 64-row fp8 panel
constexpr unsigned WAVES_PER_LAUNCH = (unsigned)NBLK * 4u;

// workspace layout (bytes)
constexpr size_t OFF_XB  = 0;                          // fp8 X  [N*D]  fragment-major
constexpr size_t OFF_YB  = (size_t)N * D;              // fp8 Y  [N*D]  fragment-major
constexpr size_t OFF_SQX = OFF_YB + (size_t)N * D;     // fp32 ||x_i||^2 [N]
constexpr size_t OFF_SQY = OFF_SQX + (size_t)N * 4;
constexpr size_t OFF_SX  = OFF_SQY + (size_t)N * 4;    // fp32 row sums KX [N]
constexpr size_t OFF_SY  = OFF_SX + (size_t)N * 4;     // fp32 row sums KY [N]
constexpr size_t OFF_T1  = OFF_SY + (size_t)N * 4;     // fp32 scalar sum(KX*KY)
constexpr size_t WS_NEED = OFF_T1 + 4;

// FRAGMENT-MAJOR ws layout: element (row r, k) of a 64x64B slice lives at
//   nib*1024 + quad*256 + cl*16 + pass*8 + j
// with nib=(r>>4)&3, cl=r&15, quad=(k>>3)&3, pass=k>>5, j=k&7.
// An MFMA operand fragment (16 rows x 64B of K) is a CONTIGUOUS 1KB at
// fragment base + lane*16 -- one coalesced global_load_dwordx4 per lane.
//
// R21 (retry; previous submission hit a container-infra failure, never ran).
// BACK TO THE RIDGE. Measured map of the (VGPR x TLP) space:
//   R18  520 blks, VGPR104:        ~4 waves/CU  -> main 88us
//   R16 2080 blks, VGPR~104:       ~16 waves/CU -> main ~33us   << optimum
//   R19 cap 64:   VGPR 32 + 18.7MB scratch      -> main 233us
//   R20 cap 85:   VGPR 40 + acc in AGPR         -> main 185us
// Both launch_bounds squeezes destroyed load-issue depth (compiler keeps
// only ~2 fragment loads in flight at VGPR<=40 -> full ~600cy L2/L3 wait
// per pair). The optimum needs VGPR ~104 (8 in-flight fragment loads) AND
// 4 waves/SIMD. That is exactly R16's natural allocation -- restore it
// verbatim and stop fighting the register allocator.
// Only change vs R16: final_kernel fused in via the monotonic __device__
// per-wave counter (bit-exact through R18/R19/R20), removing one dispatch
// and one stream boundary.
constexpr float D2_SKIP = 240.f;

typedef __attribute__((ext_vector_type(4))) float floatx4;
typedef __attribute__((ext_vector_type(2))) long longx2;

__device__ unsigned g_done;   // zero-initialized at module load; monotonic

__device__ inline unsigned short bf16bits(float f) {
  return __builtin_bit_cast(unsigned short, __float2bfloat16(f));
}

// fp32 -> fp8 e4m3 (OCP) conversion into the fragment-major layout + exact
// fp32 row squared norms. One wave per row; lane handles 8 consecutive
// elements -> one 8B store. Also zeroes sX/sY/T1.
__global__ void prep_kernel(const float* __restrict__ X, const float* __restrict__ Y,
                            unsigned char* __restrict__ Xf8, unsigned char* __restrict__ Yf8,
                            float* __restrict__ sqX, float* __restrict__ sqY,
                            float* __restrict__ sX, float* __restrict__ sY,
                            float* __restrict__ T1) {
  const int wave = threadIdx.x >> 6, lane = threadIdx.x & 63;
  const int row = blockIdx.x * 4 + wave;
  const int m = blockIdx.y;
  const float* __restrict__ src = m ? Y : X;
  unsigned char* __restrict__ dst = m ? Yf8 : Xf8;
  float* __restrict__ dsq = m ? sqY : sqX;

  if (threadIdx.x < 4) {
    float* z = m ? sY : sX;
    z[blockIdx.x * 4 + threadIdx.x] = 0.f;
  }
  if (blockIdx.x == 0 && m == 0 && threadIdx.x == 0) *T1 = 0.f;

  const float4* s4 = (const float4*)(src + (size_t)row * D);
  float4 v0 = s4[lane * 2];
  float4 v1 = s4[lane * 2 + 1];
  float acc = v0.x * v0.x + v0.y * v0.y + v0.z * v0.z + v0.w * v0.w
            + v1.x * v1.x + v1.y * v1.y + v1.z * v1.z + v1.w * v1.w;

  unsigned int w0 = 0, w1 = 0;
  w0 = __builtin_amdgcn_cvt_pk_fp8_f32(v0.x, v0.y, w0, false);
  w0 = __builtin_amdgcn_cvt_pk_fp8_f32(v0.z, v0.w, w0, true);
  w1 = __builtin_amdgcn_cvt_pk_fp8_f32(v1.x, v1.y, w1, false);
  w1 = __builtin_amdgcn_cvt_pk_fp8_f32(v1.z, v1.w, w1, true);
  const unsigned long long pk =
      (unsigned long long)w0 | ((unsigned long long)w1 << 32);

  // destination: k = lane*8 .. +8 of this row, fragment-major address
  const int p    = row >> 6;          // 64-row panel
  const int nib  = (row >> 4) & 3;
  const int cl   = row & 15;
  const int ks   = lane >> 3;         // 64-byte k-slice
  const int pass = (lane >> 2) & 1;
  const int quad = lane & 3;
  const size_t off = (size_t)p * PANELB + (size_t)ks * TILEB +
                     nib * 1024 + quad * 256 + cl * 16 + pass * 8;
  *(unsigned long long*)(dst + off) = pk;

#pragma unroll
  for (int mm = 32; mm >= 1; mm >>= 1) acc += __shfl_xor(acc, mm, 64);
  if (lane == 0) dsq[row] = acc;
}

// Upper-triangular fused Gram+RBF+reductions+final. 2080 blocks of 256
// threads; 2x2 waves of 32x32 per 64x64 tile; operands read directly from
// fragment-major global (L2/L3-hot). R16's natural allocation: no reg cap
// beyond (256,4); compiler lands ~104 VGPR -> 4 waves/SIMD, 8 in-flight
// fragment loads per k-iter.
__launch_bounds__(256, 4)
__global__ void hsic_main(const unsigned char* __restrict__ Xf8,
                          const unsigned char* __restrict__ Yf8,
                          const float* __restrict__ sqX, const float* __restrict__ sqY,
                          float* __restrict__ sX, float* __restrict__ sY,
                          float* __restrict__ T1, float* __restrict__ out) {
  // XCD-contiguous segment swizzle (bijection on [0,2080): 2080 = 8*260)
  const int b = blockIdx.x;
  int idx = (b & 7) * (NBLK / 8) + (b >> 3);

  // triangular decode: idx -> (bI, bJ) with bJ >= bI (row-major triangle)
  const float nf = (float)NB + 0.5f;
  int bI = (int)(nf - sqrtf(nf * nf - 2.0f * (float)idx));
  if (bI < 0) bI = 0;
  if (bI >= NB) bI = NB - 1;
  while (bI * NB - bI * (bI - 1) / 2 > idx) --bI;
  while ((bI + 1) * NB - (bI + 1) * bI / 2 <= idx) ++bI;
  const int bJ = bI + (idx - (bI * NB - bI * (bI - 1) / 2));
  const bool offdiag = (bI != bJ);

  const int tid = threadIdx.x;
  const int lane = tid & 63, wave = tid >> 6;
  const int wm = wave >> 1, wn = wave & 1;   // 2x2 wave grid, each wave 32x32
  const int quad = lane >> 4, cl = lane & 15;
  const int lane16 = lane << 4;

  const unsigned char* gAx = Xf8 + (size_t)bI * PANELB + wm * 2048 + lane16;
  const unsigned char* gBx = Xf8 + (size_t)bJ * PANELB + wn * 2048 + lane16;
  const unsigned char* gAy = Yf8 + (size_t)bI * PANELB + wm * 2048 + lane16;
  const unsigned char* gBy = Yf8 + (size_t)bJ * PANELB + wn * 2048 + lane16;

  floatx4 acc[2][2];
#pragma unroll
  for (int i = 0; i < 2; ++i)
#pragma unroll
    for (int j = 0; j < 2; ++j) acc[i][j] = (floatx4){0.f, 0.f, 0.f, 0.f};

  const int Ib = bI * BM + wm * 32;
  const int Jb = bJ * BM + wn * 32;

  // X-phase results carried into the Y epilogue:
  unsigned int kxp[2][2][2];   // kx packed as bf16 pairs (exact for 0/1)
  unsigned int fmask = 0;      // per-fragment wave-uniform "kx nonzero" bits
  float t1l = 0.f;

  // ---- X phase: 8 k-slices, operands straight from global ----
#pragma unroll
  for (int ks = 0; ks < KITERS; ++ks) {
    longx2 af[2], bf[2];
#pragma unroll
    for (int mi = 0; mi < 2; ++mi)
      af[mi] = *(const longx2*)(gAx + (size_t)ks * TILEB + mi * 1024);
#pragma unroll
    for (int ni = 0; ni < 2; ++ni)
      bf[ni] = *(const longx2*)(gBx + (size_t)ks * TILEB + ni * 1024);
#pragma unroll
    for (int mi = 0; mi < 2; ++mi)
#pragma unroll
      for (int ni = 0; ni < 2; ++ni) {
        acc[mi][ni] = __builtin_amdgcn_mfma_f32_16x16x32_fp8_fp8(af[mi][0], bf[ni][0], acc[mi][ni], 0, 0, 0);
        acc[mi][ni] = __builtin_amdgcn_mfma_f32_16x16x32_fp8_fp8(af[mi][1], bf[ni][1], acc[mi][ni], 0, 0, 0);
      }
  }

  // ---- X epilogue: acc -> kx; sX atomics; pack kx; reset acc ----
  // C/D layout (m89): col = lane&15, row = quad*4 + reg
  {
    float rx[2][4];
    float cx[2];
#pragma unroll
    for (int mi = 0; mi < 2; ++mi)
#pragma unroll
      for (int r = 0; r < 4; ++r) rx[mi][r] = 0.f;
#pragma unroll
    for (int ni = 0; ni < 2; ++ni) cx[ni] = 0.f;

#pragma unroll
    for (int mi = 0; mi < 2; ++mi) {
      const int ig0 = Ib + mi * 16 + quad * 4;
      float sxi[4];
#pragma unroll
      for (int r = 0; r < 4; ++r) sxi[r] = sqX[ig0 + r];
#pragma unroll
      for (int ni = 0; ni < 2; ++ni) {
        const int jg = Jb + ni * 16 + cl;
        const float sxj = sqX[jg];
        float d2x[4];
        bool lflag = false;
#pragma unroll
        for (int r = 0; r < 4; ++r) {
          const int ig = ig0 + r;
          d2x[r] = sxi[r] + sxj - 2.f * acc[mi][ni][r];
          lflag |= (d2x[r] < D2_SKIP) | (ig == jg);
        }
        float kxv[4] = {0.f, 0.f, 0.f, 0.f};
        if (__any(lflag)) {   // wave-uniform; skipped frags are exactly 0
          fmask |= (1u << (mi * 2 + ni));
#pragma unroll
          for (int r = 0; r < 4; ++r) {
            const int ig = ig0 + r;
            kxv[r] = (ig == jg) ? 1.f : __expf(-0.5f * d2x[r]);
            rx[mi][r] += kxv[r];
            cx[ni] += kxv[r];
          }
        }
        kxp[mi][ni][0] = (unsigned)bf16bits(kxv[0]) | ((unsigned)bf16bits(kxv[1]) << 16);
        kxp[mi][ni][1] = (unsigned)bf16bits(kxv[2]) | ((unsigned)bf16bits(kxv[3]) << 16);
        // reset acc for the Y phase
        acc[mi][ni] = (floatx4){0.f, 0.f, 0.f, 0.f};
      }
    }

    if (fmask != 0) {
      // row sums: reduce across the 16 columns (lanes cl=0..15 per quad)
#pragma unroll
      for (int mi = 0; mi < 2; ++mi)
#pragma unroll
        for (int r = 0; r < 4; ++r) {
          float vx = rx[mi][r];
#pragma unroll
          for (int mm = 1; mm < 16; mm <<= 1) vx += __shfl_xor(vx, mm, 16);
          rx[mi][r] = vx;
        }
      if (cl == 0) {
#pragma unroll
        for (int mi = 0; mi < 2; ++mi)
#pragma unroll
          for (int r = 0; r < 4; ++r)
            atomicAdd(&sX[Ib + mi * 16 + quad * 4 + r], rx[mi][r]);
      }
      if (offdiag) {
#pragma unroll
        for (int ni = 0; ni < 2; ++ni) {
          float vx = cx[ni];
          vx += __shfl_xor(vx, 16, 64);
          vx += __shfl_xor(vx, 32, 64);
          if (quad == 0) atomicAdd(&sX[Jb + ni * 16 + cl], vx);
        }
      }
    }
  }

  // ---- Y phase ----
#pragma unroll
  for (int ks = 0; ks < KITERS; ++ks) {
    longx2 af[2], bf[2];
#pragma unroll
    for (int mi = 0; mi < 2; ++mi)
      af[mi] = *(const longx2*)(gAy + (size_t)ks * TILEB + mi * 1024);
#pragma unroll
    for (int ni = 0; ni < 2; ++ni)
      bf[ni] = *(const longx2*)(gBy + (size_t)ks * TILEB + ni * 1024);
#pragma unroll
    for (int mi = 0; mi < 2; ++mi)
#pragma unroll
      for (int ni = 0; ni < 2; ++ni) {
        acc[mi][ni] = __builtin_amdgcn_mfma_f32_16x16x32_fp8_fp8(af[mi][0], bf[ni][0], acc[mi][ni], 0, 0, 0);
        acc[mi][ni] = __builtin_amdgcn_mfma_f32_16x16x32_fp8_fp8(af[mi][1], bf[ni][1], acc[mi][ni], 0, 0, 0);
      }
  }

  // ---- Y epilogue ----
  {
    float ry[2][4];
    float cy[2];
    bool anyy = false;
#pragma unroll
    for (int mi = 0; mi < 2; ++mi)
#pragma unroll
      for (int r = 0; r < 4; ++r) ry[mi][r] = 0.f;
#pragma unroll
    for (int ni = 0; ni < 2; ++ni) cy[ni] = 0.f;

#pragma unroll
    for (int mi = 0; mi < 2; ++mi) {
      const int ig0 = Ib + mi * 16 + quad * 4;
      float syi[4];
#pragma unroll
      for (int r = 0; r < 4; ++r) syi[r] = sqY[ig0 + r];
#pragma unroll
      for (int ni = 0; ni < 2; ++ni) {
        const int jg = Jb + ni * 16 + cl;
        const float syj = sqY[jg];
        float d2y[4];
        bool lflag = false;
#pragma unroll
        for (int r = 0; r < 4; ++r) {
          const int ig = ig0 + r;
          d2y[r] = syi[r] + syj - 2.f * acc[mi][ni][r];
          lflag |= (d2y[r] < D2_SKIP) | (ig == jg);
        }
        const bool xb = (fmask >> (mi * 2 + ni)) & 1u;  // wave-uniform
        if (__any(lflag) || xb) {
          anyy = true;
          float kyv[4];
#pragma unroll
          for (int r = 0; r < 4; ++r) {
            const int ig = ig0 + r;
            kyv[r] = (ig == jg) ? 1.f : __expf(-0.5f * d2y[r]);
            ry[mi][r] += kyv[r];
            cy[ni] += kyv[r];
          }
          if (xb) {
            const float kx0 = __builtin_bit_cast(float, (kxp[mi][ni][0] & 0xFFFFu) << 16);
            const float kx1 = __builtin_bit_cast(float, kxp[mi][ni][0] & 0xFFFF0000u);
            const float kx2 = __builtin_bit_cast(float, (kxp[mi][ni][1] & 0xFFFFu) << 16);
            const float kx3 = __builtin_bit_cast(float, kxp[mi][ni][1] & 0xFFFF0000u);
            t1l += kx0 * kyv[0] + kx1 * kyv[1] + kx2 * kyv[2] + kx3 * kyv[3];
          }
        }
      }
    }

    if (anyy) {
#pragma unroll
      for (int mi = 0; mi < 2; ++mi)
#pragma unroll
        for (int r = 0; r < 4; ++r) {
          float vy = ry[mi][r];
#pragma unroll
          for (int mm = 1; mm < 16; mm <<= 1) vy += __shfl_xor(vy, mm, 16);
          ry[mi][r] = vy;
        }
      if (cl == 0) {
#pragma unroll
        for (int mi = 0; mi < 2; ++mi)
#pragma unroll
          for (int r = 0; r < 4; ++r)
            atomicAdd(&sY[Ib + mi * 16 + quad * 4 + r], ry[mi][r]);
      }
      if (offdiag) {
#pragma unroll
        for (int ni = 0; ni < 2; ++ni) {
          float vy = cy[ni];
          vy += __shfl_xor(vy, 16, 64);
          vy += __shfl_xor(vy, 32, 64);
          if (quad == 0) atomicAdd(&sY[Jb + ni * 16 + cl], vy);
        }
      }
    }
  }

  // T1 wave reduction (off-diagonal tiles count twice by symmetry)
  if (fmask != 0) {
    t1l *= offdiag ? 2.f : 1.f;
#pragma unroll
    for (int mm = 1; mm < 64; mm <<= 1) t1l += __shfl_xor(t1l, mm, 64);
    if (lane == 0 && t1l != 0.f) atomicAdd(T1, t1l);
  }

  // ---- fused final: per-WAVE completion counter; last wave computes HSIC.
  // All prior device-scope atomics are ordered before the release
  // fetch_add; the last wave's acquire makes them visible. g_done is a
  // __device__ global: unaffected by workspace poison, monotonic across
  // launches and rocprof replays (each launch adds exactly WAVES_PER_LAUNCH).
  int am_last = 0;
  if (lane == 0) {
    unsigned old = __hip_atomic_fetch_add(&g_done, 1u, __ATOMIC_ACQ_REL,
                                          __HIP_MEMORY_SCOPE_AGENT);
    am_last = ((old + 1u) % WAVES_PER_LAUNCH) == 0u;
  }
  am_last = __shfl(am_last, 0, 64);
  if (am_last) {
    float dp = 0.f, sa = 0.f, sb = 0.f;
    for (int i = lane * 4; i < N; i += 256) {
      const float4 a4 = *(const float4*)&sX[i];
      const float4 b4 = *(const float4*)&sY[i];
      dp += a4.x * b4.x + a4.y * b4.y + a4.z * b4.z + a4.w * b4.w;
      sa += a4.x + a4.y + a4.z + a4.w;
      sb += b4.x + b4.y + b4.z + b4.w;
    }
#pragma unroll
    for (int mm = 1; mm < 64; mm <<= 1) {
      dp += __shfl_xor(dp, mm, 64);
      sa += __shfl_xor(sa, mm, 64);
      sb += __shfl_xor(sb, mm, 64);
    }
    if (lane == 0) {
      const float t1 = __hip_atomic_load(T1, __ATOMIC_RELAXED, __HIP_MEMORY_SCOPE_AGENT);
      const float n = (float)N;
      const float total = t1 - (2.f / n) * dp + (sa * sb) / (n * n);
      out[0] = total / ((n - 1.f) * (n - 1.f));
    }
  }
}

}  // namespace

extern "C" void kernel_launch(void* const* d_in, const int* in_sizes, int n_in,
                              void* d_out, int out_size, void* d_ws, size_t ws_size,
                              hipStream_t stream) {
  const float* X = (const float*)d_in[0];
  const float* Y = (const float*)d_in[1];
  char* ws = (char*)d_ws;
  if (ws_size < WS_NEED) return;

  unsigned char* Xf8 = (unsigned char*)(ws + OFF_XB);
  unsigned char* Yf8 = (unsigned char*)(ws + OFF_YB);
  float* sqX = (float*)(ws + OFF_SQX);
  float* sqY = (float*)(ws + OFF_SQY);
  float* sX  = (float*)(ws + OFF_SX);
  float* sY  = (float*)(ws + OFF_SY);
  float* T1  = (float*)(ws + OFF_T1);
  float* out = (float*)d_out;

  prep_kernel<<<dim3(N / 4, 2), 256, 0, stream>>>(X, Y, Xf8, Yf8, sqX, sqY, sX, sY, T1);
  hsic_main<<<NBLK, 256, 0, stream>>>(Xf8, Yf8, sqX, sqY, sX, sY, T1, out);
}

// Round 10
// 91.094 us; speedup vs baseline: 3.2869x; 2.4777x over previous
//
#include <hip/hip_runtime.h>
#include <hip/hip_bf16.h>

namespace {

constexpr int N = 4096;
constexpr int D = 512;
constexpr int BM = 64;    // block tile 64x64; 2080 blocks, 2x2 waves of 32x32
constexpr int BK = 64;    // K-step per fragment column-slice (64 fp8 bytes)
constexpr int KITERS = D / BK;  // 8 per phase
constexpr int NB = N / BM;      // 64 block-rows
constexpr int NBLK = NB * (NB + 1) / 2;  // 2080 upper-tri tiles (= 8 * 260)
constexpr int TILEB = BM * BK;  // 4 KB: one 64-row x 64-byte k-slice
constexpr int PANELB = BM * D;  // 32 KB: one 64-row fp8 panel

// workspace layout (bytes)
constexpr size_t OFF_XB  = 0;                          // fp8 X  [N*D]  fragment-major
constexpr size_t OFF_YB  = (size_t)N * D;              // fp8 Y  [N*D]  fragment-major
constexpr size_t OFF_SQX = OFF_YB + (size_t)N * D;     // fp32 ||x_i||^2 [N]
constexpr size_t OFF_SQY = OFF_SQX + (size_t)N * 4;
constexpr size_t OFF_SX  = OFF_SQY + (size_t)N * 4;    // fp32 row sums KX [N]
constexpr size_t OFF_SY  = OFF_SX + (size_t)N * 4;     // fp32 row sums KY [N]
constexpr size_t OFF_T1  = OFF_SY + (size_t)N * 4;     // fp32 scalar sum(KX*KY)
constexpr size_t WS_NEED = OFF_T1 + 4;

// FRAGMENT-MAJOR ws layout: element (row r, k) of a 64x64B slice lives at
//   nib*1024 + quad*256 + cl*16 + pass*8 + j
// with nib=(r>>4)&3, cl=r&15, quad=(k>>3)&3, pass=k>>5, j=k&7.
// An MFMA operand fragment (16 rows x 64B of K) is a CONTIGUOUS 1KB at
// fragment base + lane*16 -- one coalesced global_load_dwordx4 per lane.
//
// R22b: ASM-PINNED DEPTH-2 LOAD PIPELINE (compile-fixed).
// R22's "s"-constraint saddr form failed: the base derives from threadIdx
// (wm/wn) so the compiler can't prove uniformity and materialized it in
// VGPRs -> invalid 32b-voffset+VGPR-saddr encoding. Fix: 64-bit VGPR
// address form `global_load_dwordx4 vdst, v[a:a+1], off offset:1024`,
// per-lane addresses computed in C. Schedule identical to R22's design:
// Evidence ladder: every compiler-scheduled variant plateaus at main~35us
// (4-8x the MFMA floor) or worse; the compiler ALWAYS reconstructs the
// serial load->wait->MFMA chain (R18 deleted a 2-set reg pipeline; R19/
// R20/R21 showed launch-bound caps / tail code flip the allocator into
// 32-48 VGPR + AGPR-acc with 2-deep load issue -> 167-233us). R21's fused
// tail alone changed loop VGPR 104->48 (rule-19 instability) -> fused
// final is DEAD; back to 3 kernels.
// The fix the compiler cannot undo (T4/AITER pattern): inline-asm volatile
// global_load_dwordx4 issuing set k+1 BEFORE the MFMAs of set k, manual
// "s_waitcnt vmcnt(4)" carrying the consumed fragments as "+v" operands
// (dependence pins MFMAs behind the wait) + sched_barrier(0) (rule 18).
// Fully unrolled 16 steps, named P/Q sets (rule 20). Epilogue VMEM
// (sqX loads, atomics) is FIFO-NEWER than our outstanding prefetch, so
// vmcnt(4) can only over-wait, never under-wait. Last step drains
// vmcnt(0). MFMA order identical to R16 -> bit-identical accumulators.
constexpr float D2_SKIP = 240.f;

typedef __attribute__((ext_vector_type(4))) float floatx4;
typedef __attribute__((ext_vector_type(2))) long longx2;

__device__ inline unsigned short bf16bits(float f) {
  return __builtin_bit_cast(unsigned short, __float2bfloat16(f));
}

// fp32 -> fp8 e4m3 (OCP) conversion into the fragment-major layout + exact
// fp32 row squared norms. One wave per row; lane handles 8 consecutive
// elements -> one 8B store. Also zeroes sX/sY/T1.
__global__ void prep_kernel(const float* __restrict__ X, const float* __restrict__ Y,
                            unsigned char* __restrict__ Xf8, unsigned char* __restrict__ Yf8,
                            float* __restrict__ sqX, float* __restrict__ sqY,
                            float* __restrict__ sX, float* __restrict__ sY,
                            float* __restrict__ T1) {
  const int wave = threadIdx.x >> 6, lane = threadIdx.x & 63;
  const int row = blockIdx.x * 4 + wave;
  const int m = blockIdx.y;
  const float* __restrict__ src = m ? Y : X;
  unsigned char* __restrict__ dst = m ? Yf8 : Xf8;
  float* __restrict__ dsq = m ? sqY : sqX;

  if (threadIdx.x < 4) {
    float* z = m ? sY : sX;
    z[blockIdx.x * 4 + threadIdx.x] = 0.f;
  }
  if (blockIdx.x == 0 && m == 0 && threadIdx.x == 0) *T1 = 0.f;

  const float4* s4 = (const float4*)(src + (size_t)row * D);
  float4 v0 = s4[lane * 2];
  float4 v1 = s4[lane * 2 + 1];
  float acc = v0.x * v0.x + v0.y * v0.y + v0.z * v0.z + v0.w * v0.w
            + v1.x * v1.x + v1.y * v1.y + v1.z * v1.z + v1.w * v1.w;

  unsigned int w0 = 0, w1 = 0;
  w0 = __builtin_amdgcn_cvt_pk_fp8_f32(v0.x, v0.y, w0, false);
  w0 = __builtin_amdgcn_cvt_pk_fp8_f32(v0.z, v0.w, w0, true);
  w1 = __builtin_amdgcn_cvt_pk_fp8_f32(v1.x, v1.y, w1, false);
  w1 = __builtin_amdgcn_cvt_pk_fp8_f32(v1.z, v1.w, w1, true);
  const unsigned long long pk =
      (unsigned long long)w0 | ((unsigned long long)w1 << 32);

  // destination: k = lane*8 .. +8 of this row, fragment-major address
  const int p    = row >> 6;          // 64-row panel
  const int nib  = (row >> 4) & 3;
  const int cl   = row & 15;
  const int ks   = lane >> 3;         // 64-byte k-slice
  const int pass = (lane >> 2) & 1;
  const int quad = lane & 3;
  const size_t off = (size_t)p * PANELB + (size_t)ks * TILEB +
                     nib * 1024 + quad * 256 + cl * 16 + pass * 8;
  *(unsigned long long*)(dst + off) = pk;

#pragma unroll
  for (int mm = 32; mm >= 1; mm >>= 1) acc += __shfl_xor(acc, mm, 64);
  if (lane == 0) dsq[row] = acc;
}

// --- asm pipeline primitives -------------------------------------------
// 4 async 16B loads via 64-bit VGPR addresses:
//   A0 <- [PA], A1 <- [PA+1024], B0 <- [PB], B1 <- [PB+1024]
#define ISSUE4(A0, A1, B0, B1, PA, PB)                                       \
  asm volatile("global_load_dwordx4 %0, %4, off\n\t"                         \
               "global_load_dwordx4 %1, %4, off offset:1024\n\t"             \
               "global_load_dwordx4 %2, %5, off\n\t"                         \
               "global_load_dwordx4 %3, %5, off offset:1024"                 \
               : "=&v"(A0), "=&v"(A1), "=&v"(B0), "=&v"(B1)                  \
               : "v"(PA), "v"(PB)                                            \
               : "memory")

// wait until <=CNT VMEM outstanding; "+v" ties the consumed fragments to
// this asm so the MFMAs below cannot be scheduled above it (rule 18), plus
// an explicit sched_barrier.
#define WAIT4(A0, A1, B0, B1, CNT)                                           \
  asm volatile("s_waitcnt vmcnt(" CNT ")"                                    \
               : "+v"(A0), "+v"(A1), "+v"(B0), "+v"(B1)                      \
               :                                                             \
               : "memory");                                                  \
  __builtin_amdgcn_sched_barrier(0)

// 16 MFMAs in R16's exact order: (mi,ni) = (0,0),(0,1),(1,0),(1,1), two
// k-halves each -> bit-identical accumulation.
#define MFMA_SET(A0, A1, B0, B1)                                                                  \
  do {                                                                                            \
    acc[0][0] = __builtin_amdgcn_mfma_f32_16x16x32_fp8_fp8((A0)[0], (B0)[0], acc[0][0], 0, 0, 0); \
    acc[0][0] = __builtin_amdgcn_mfma_f32_16x16x32_fp8_fp8((A0)[1], (B0)[1], acc[0][0], 0, 0, 0); \
    acc[0][1] = __builtin_amdgcn_mfma_f32_16x16x32_fp8_fp8((A0)[0], (B1)[0], acc[0][1], 0, 0, 0); \
    acc[0][1] = __builtin_amdgcn_mfma_f32_16x16x32_fp8_fp8((A0)[1], (B1)[1], acc[0][1], 0, 0, 0); \
    acc[1][0] = __builtin_amdgcn_mfma_f32_16x16x32_fp8_fp8((A1)[0], (B0)[0], acc[1][0], 0, 0, 0); \
    acc[1][0] = __builtin_amdgcn_mfma_f32_16x16x32_fp8_fp8((A1)[1], (B0)[1], acc[1][0], 0, 0, 0); \
    acc[1][1] = __builtin_amdgcn_mfma_f32_16x16x32_fp8_fp8((A1)[0], (B1)[0], acc[1][1], 0, 0, 0); \
    acc[1][1] = __builtin_amdgcn_mfma_f32_16x16x32_fp8_fp8((A1)[1], (B1)[1], acc[1][1], 0, 0, 0); \
  } while (0)

// one steady-state step: issue set(k+1) into I* from addresses PA/PB, wait
// for U* (the 4 newest in flight are I*), compute on U*.
#define STEP(IA0, IA1, IB0, IB1, UA0, UA1, UB0, UB1, PA, PB)                 \
  ISSUE4(IA0, IA1, IB0, IB1, PA, PB);                                        \
  WAIT4(UA0, UA1, UB0, UB1, "4");                                            \
  MFMA_SET(UA0, UA1, UB0, UB1)

// Upper-triangular fused Gram+RBF+reductions. 2080 blocks of 256 threads;
// 2x2 waves of 32x32 per 64x64 tile; operands read directly from the
// fragment-major global buffers via the asm-pinned depth-2 pipeline.
__launch_bounds__(256, 4)
__global__ void hsic_main(const unsigned char* __restrict__ Xf8,
                          const unsigned char* __restrict__ Yf8,
                          const float* __restrict__ sqX, const float* __restrict__ sqY,
                          float* __restrict__ sX, float* __restrict__ sY,
                          float* __restrict__ T1) {
  // XCD-contiguous segment swizzle (bijection on [0,2080): 2080 = 8*260)
  const int b = blockIdx.x;
  int idx = (b & 7) * (NBLK / 8) + (b >> 3);

  // triangular decode: idx -> (bI, bJ) with bJ >= bI (row-major triangle)
  const float nf = (float)NB + 0.5f;
  int bI = (int)(nf - sqrtf(nf * nf - 2.0f * (float)idx));
  if (bI < 0) bI = 0;
  if (bI >= NB) bI = NB - 1;
  while (bI * NB - bI * (bI - 1) / 2 > idx) --bI;
  while ((bI + 1) * NB - (bI + 1) * bI / 2 <= idx) ++bI;
  const int bJ = bI + (idx - (bI * NB - bI * (bI - 1) / 2));
  const bool offdiag = (bI != bJ);

  const int tid = threadIdx.x;
  const int lane = tid & 63, wave = tid >> 6;
  const int wm = wave >> 1, wn = wave & 1;   // 2x2 wave grid, each wave 32x32
  const int quad = lane >> 4, cl = lane & 15;
  const int lane16 = lane << 4;

  // per-lane fragment addresses (the +1024 sibling folds into the asm's
  // offset immediate; the k-slice advance is +TILEB per step, added in C)
  const unsigned char* pAx = Xf8 + (size_t)bI * PANELB + wm * 2048 + lane16;
  const unsigned char* pBx = Xf8 + (size_t)bJ * PANELB + wn * 2048 + lane16;
  const unsigned char* pAy = Yf8 + (size_t)bI * PANELB + wm * 2048 + lane16;
  const unsigned char* pBy = Yf8 + (size_t)bJ * PANELB + wn * 2048 + lane16;

  floatx4 acc[2][2];
#pragma unroll
  for (int i = 0; i < 2; ++i)
#pragma unroll
    for (int j = 0; j < 2; ++j) acc[i][j] = (floatx4){0.f, 0.f, 0.f, 0.f};

  const int Ib = bI * BM + wm * 32;
  const int Jb = bJ * BM + wn * 32;

  // X-phase results carried into the Y epilogue:
  unsigned int kxp[2][2][2];   // kx packed as bf16 pairs (exact for 0/1)
  unsigned int fmask = 0;      // per-fragment wave-uniform "kx nonzero" bits
  float t1l = 0.f;

  longx2 aP0, aP1, bP0, bP1, aQ0, aQ1, bQ0, bQ1;

  // ---- X phase: depth-2 pipeline, fully unrolled ----
  ISSUE4(aP0, aP1, bP0, bP1, pAx + 0 * TILEB, pBx + 0 * TILEB);                      // P <- X0
  STEP(aQ0, aQ1, bQ0, bQ1, aP0, aP1, bP0, bP1, pAx + 1 * TILEB, pBx + 1 * TILEB);   // k0
  STEP(aP0, aP1, bP0, bP1, aQ0, aQ1, bQ0, bQ1, pAx + 2 * TILEB, pBx + 2 * TILEB);   // k1
  STEP(aQ0, aQ1, bQ0, bQ1, aP0, aP1, bP0, bP1, pAx + 3 * TILEB, pBx + 3 * TILEB);   // k2
  STEP(aP0, aP1, bP0, bP1, aQ0, aQ1, bQ0, bQ1, pAx + 4 * TILEB, pBx + 4 * TILEB);   // k3
  STEP(aQ0, aQ1, bQ0, bQ1, aP0, aP1, bP0, bP1, pAx + 5 * TILEB, pBx + 5 * TILEB);   // k4
  STEP(aP0, aP1, bP0, bP1, aQ0, aQ1, bQ0, bQ1, pAx + 6 * TILEB, pBx + 6 * TILEB);   // k5
  STEP(aQ0, aQ1, bQ0, bQ1, aP0, aP1, bP0, bP1, pAx + 7 * TILEB, pBx + 7 * TILEB);   // k6
  STEP(aP0, aP1, bP0, bP1, aQ0, aQ1, bQ0, bQ1, pAy + 0 * TILEB, pBy + 0 * TILEB);   // k7: prefetch Y0

  // ---- X epilogue: acc -> kx; sX atomics; pack kx; reset acc ----
  // (compiler VMEM here is FIFO-newer than our outstanding P prefetch,
  // so its conservative waitcnts remain correct.)
  // C/D layout (m89): col = lane&15, row = quad*4 + reg
  {
    float rx[2][4];
    float cx[2];
#pragma unroll
    for (int mi = 0; mi < 2; ++mi)
#pragma unroll
      for (int r = 0; r < 4; ++r) rx[mi][r] = 0.f;
#pragma unroll
    for (int ni = 0; ni < 2; ++ni) cx[ni] = 0.f;

#pragma unroll
    for (int mi = 0; mi < 2; ++mi) {
      const int ig0 = Ib + mi * 16 + quad * 4;
      float sxi[4];
#pragma unroll
      for (int r = 0; r < 4; ++r) sxi[r] = sqX[ig0 + r];
#pragma unroll
      for (int ni = 0; ni < 2; ++ni) {
        const int jg = Jb + ni * 16 + cl;
        const float sxj = sqX[jg];
        float d2x[4];
        bool lflag = false;
#pragma unroll
        for (int r = 0; r < 4; ++r) {
          const int ig = ig0 + r;
          d2x[r] = sxi[r] + sxj - 2.f * acc[mi][ni][r];
          lflag |= (d2x[r] < D2_SKIP) | (ig == jg);
        }
        float kxv[4] = {0.f, 0.f, 0.f, 0.f};
        if (__any(lflag)) {   // wave-uniform; skipped frags are exactly 0
          fmask |= (1u << (mi * 2 + ni));
#pragma unroll
          for (int r = 0; r < 4; ++r) {
            const int ig = ig0 + r;
            kxv[r] = (ig == jg) ? 1.f : __expf(-0.5f * d2x[r]);
            rx[mi][r] += kxv[r];
            cx[ni] += kxv[r];
          }
        }
        kxp[mi][ni][0] = (unsigned)bf16bits(kxv[0]) | ((unsigned)bf16bits(kxv[1]) << 16);
        kxp[mi][ni][1] = (unsigned)bf16bits(kxv[2]) | ((unsigned)bf16bits(kxv[3]) << 16);
        // reset acc for the Y phase
        acc[mi][ni] = (floatx4){0.f, 0.f, 0.f, 0.f};
      }
    }

    if (fmask != 0) {
      // row sums: reduce across the 16 columns (lanes cl=0..15 per quad)
#pragma unroll
      for (int mi = 0; mi < 2; ++mi)
#pragma unroll
        for (int r = 0; r < 4; ++r) {
          float vx = rx[mi][r];
#pragma unroll
          for (int mm = 1; mm < 16; mm <<= 1) vx += __shfl_xor(vx, mm, 16);
          rx[mi][r] = vx;
        }
      if (cl == 0) {
#pragma unroll
        for (int mi = 0; mi < 2; ++mi)
#pragma unroll
          for (int r = 0; r < 4; ++r)
            atomicAdd(&sX[Ib + mi * 16 + quad * 4 + r], rx[mi][r]);
      }
      if (offdiag) {
#pragma unroll
        for (int ni = 0; ni < 2; ++ni) {
          float vx = cx[ni];
          vx += __shfl_xor(vx, 16, 64);
          vx += __shfl_xor(vx, 32, 64);
          if (quad == 0) atomicAdd(&sX[Jb + ni * 16 + cl], vx);
        }
      }
    }
  }

  // ---- Y phase (Y0 already in flight in P) ----
  STEP(aQ0, aQ1, bQ0, bQ1, aP0, aP1, bP0, bP1, pAy + 1 * TILEB, pBy + 1 * TILEB);   // y0
  STEP(aP0, aP1, bP0, bP1, aQ0, aQ1, bQ0, bQ1, pAy + 2 * TILEB, pBy + 2 * TILEB);   // y1
  STEP(aQ0, aQ1, bQ0, bQ1, aP0, aP1, bP0, bP1, pAy + 3 * TILEB, pBy + 3 * TILEB);   // y2
  STEP(aP0, aP1, bP0, bP1, aQ0, aQ1, bQ0, bQ1, pAy + 4 * TILEB, pBy + 4 * TILEB);   // y3
  STEP(aQ0, aQ1, bQ0, bQ1, aP0, aP1, bP0, bP1, pAy + 5 * TILEB, pBy + 5 * TILEB);   // y4
  STEP(aP0, aP1, bP0, bP1, aQ0, aQ1, bQ0, bQ1, pAy + 6 * TILEB, pBy + 6 * TILEB);   // y5
  STEP(aQ0, aQ1, bQ0, bQ1, aP0, aP1, bP0, bP1, pAy + 7 * TILEB, pBy + 7 * TILEB);   // y6
  WAIT4(aQ0, aQ1, bQ0, bQ1, "0");                                                   // y7: drain
  MFMA_SET(aQ0, aQ1, bQ0, bQ1);

  // ---- Y epilogue ----
  {
    float ry[2][4];
    float cy[2];
    bool anyy = false;
#pragma unroll
    for (int mi = 0; mi < 2; ++mi)
#pragma unroll
      for (int r = 0; r < 4; ++r) ry[mi][r] = 0.f;
#pragma unroll
    for (int ni = 0; ni < 2; ++ni) cy[ni] = 0.f;

#pragma unroll
    for (int mi = 0; mi < 2; ++mi) {
      const int ig0 = Ib + mi * 16 + quad * 4;
      float syi[4];
#pragma unroll
      for (int r = 0; r < 4; ++r) syi[r] = sqY[ig0 + r];
#pragma unroll
      for (int ni = 0; ni < 2; ++ni) {
        const int jg = Jb + ni * 16 + cl;
        const float syj = sqY[jg];
        float d2y[4];
        bool lflag = false;
#pragma unroll
        for (int r = 0; r < 4; ++r) {
          const int ig = ig0 + r;
          d2y[r] = syi[r] + syj - 2.f * acc[mi][ni][r];
          lflag |= (d2y[r] < D2_SKIP) | (ig == jg);
        }
        const bool xb = (fmask >> (mi * 2 + ni)) & 1u;  // wave-uniform
        if (__any(lflag) || xb) {
          anyy = true;
          float kyv[4];
#pragma unroll
          for (int r = 0; r < 4; ++r) {
            const int ig = ig0 + r;
            kyv[r] = (ig == jg) ? 1.f : __expf(-0.5f * d2y[r]);
            ry[mi][r] += kyv[r];
            cy[ni] += kyv[r];
          }
          if (xb) {
            const float kx0 = __builtin_bit_cast(float, (kxp[mi][ni][0] & 0xFFFFu) << 16);
            const float kx1 = __builtin_bit_cast(float, kxp[mi][ni][0] & 0xFFFF0000u);
            const float kx2 = __builtin_bit_cast(float, (kxp[mi][ni][1] & 0xFFFFu) << 16);
            const float kx3 = __builtin_bit_cast(float, kxp[mi][ni][1] & 0xFFFF0000u);
            t1l += kx0 * kyv[0] + kx1 * kyv[1] + kx2 * kyv[2] + kx3 * kyv[3];
          }
        }
      }
    }

    if (anyy) {
#pragma unroll
      for (int mi = 0; mi < 2; ++mi)
#pragma unroll
        for (int r = 0; r < 4; ++r) {
          float vy = ry[mi][r];
#pragma unroll
          for (int mm = 1; mm < 16; mm <<= 1) vy += __shfl_xor(vy, mm, 16);
          ry[mi][r] = vy;
        }
      if (cl == 0) {
#pragma unroll
        for (int mi = 0; mi < 2; ++mi)
#pragma unroll
          for (int r = 0; r < 4; ++r)
            atomicAdd(&sY[Ib + mi * 16 + quad * 4 + r], ry[mi][r]);
      }
      if (offdiag) {
#pragma unroll
        for (int ni = 0; ni < 2; ++ni) {
          float vy = cy[ni];
          vy += __shfl_xor(vy, 16, 64);
          vy += __shfl_xor(vy, 32, 64);
          if (quad == 0) atomicAdd(&sY[Jb + ni * 16 + cl], vy);
        }
      }
    }
  }

  // T1 wave reduction (off-diagonal tiles count twice by symmetry)
  if (fmask != 0) {
    t1l *= offdiag ? 2.f : 1.f;
#pragma unroll
    for (int mm = 1; mm < 64; mm <<= 1) t1l += __shfl_xor(t1l, mm, 64);
    if (lane == 0 && t1l != 0.f) atomicAdd(T1, t1l);
  }
}

// hsic = (T1 - (2/n) sum sX_i sY_i + (SX*SY)/n^2) / (n-1)^2
__global__ void final_kernel(const float* __restrict__ sX, const float* __restrict__ sY,
                             const float* __restrict__ T1, float* __restrict__ out) {
  const int tid = threadIdx.x;
  float dp = 0.f, sa = 0.f, sb = 0.f;
  for (int i = tid * 4; i < N; i += 1024) {
    const float4 a4 = *(const float4*)&sX[i];
    const float4 b4 = *(const float4*)&sY[i];
    dp += a4.x * b4.x + a4.y * b4.y + a4.z * b4.z + a4.w * b4.w;
    sa += a4.x + a4.y + a4.z + a4.w;
    sb += b4.x + b4.y + b4.z + b4.w;
  }
#pragma unroll
  for (int mm = 1; mm < 64; mm <<= 1) {
    dp += __shfl_xor(dp, mm, 64);
    sa += __shfl_xor(sa, mm, 64);
    sb += __shfl_xor(sb, mm, 64);
  }
  __shared__ float r0[4], r1[4], r2[4];
  if ((tid & 63) == 0) { int w = tid >> 6; r0[w] = dp; r1[w] = sa; r2[w] = sb; }
  __syncthreads();
  if (tid == 0) {
    dp = r0[0] + r0[1] + r0[2] + r0[3];
    sa = r1[0] + r1[1] + r1[2] + r1[3];
    sb = r2[0] + r2[1] + r2[2] + r2[3];
    const float n = (float)N;
    const float total = T1[0] - (2.f / n) * dp + (sa * sb) / (n * n);
    out[0] = total / ((n - 1.f) * (n - 1.f));
  }
}

}  // namespace

extern "C" void kernel_launch(void* const* d_in, const int* in_sizes, int n_in,
                              void* d_out, int out_size, void* d_ws, size_t ws_size,
                              hipStream_t stream) {
  const float* X = (const float*)d_in[0];
  const float* Y = (const float*)d_in[1];
  char* ws = (char*)d_ws;
  if (ws_size < WS_NEED) return;

  unsigned char* Xf8 = (unsigned char*)(ws + OFF_XB);
  unsigned char* Yf8 = (unsigned char*)(ws + OFF_YB);
  float* sqX = (float*)(ws + OFF_SQX);
  float* sqY = (float*)(ws + OFF_SQY);
  float* sX  = (float*)(ws + OFF_SX);
  float* sY  = (float*)(ws + OFF_SY);
  float* T1  = (float*)(ws + OFF_T1);
  float* out = (float*)d_out;

  prep_kernel<<<dim3(N / 4, 2), 256, 0, stream>>>(X, Y, Xf8, Yf8, sqX, sqY, sX, sY, T1);
  hsic_main<<<NBLK, 256, 0, stream>>>(Xf8, Yf8, sqX, sqY, sX, sY, T1);
  final_kernel<<<1, 256, 0, stream>>>(sX, sY, T1, out);
}